// Round 7
// baseline (244.366 us; speedup 1.0000x reference)
//
#include <hip/hip_runtime.h>

// ---------- types ----------
typedef _Float16 f16;
typedef _Float16 f16x4 __attribute__((ext_vector_type(4)));
typedef _Float16 f16x8 __attribute__((ext_vector_type(8)));
typedef float    f32x4 __attribute__((ext_vector_type(4)));

#define N_ROWS 100000
#define RT 1563           // 1563 * 64 = 100032 padded rows
#define LSH1 136          // h1 overlay stride (f16)
#define LSH2 72           // h2 overlay stride (f16)

// ws: weights only
#define W1T_OFF 0
#define W1T_BYTES (256 * 256 * 2)
#define W2T_OFF W1T_BYTES

__device__ __forceinline__ void glds16(const void* g, void* l) {
    __builtin_amdgcn_global_load_lds((const __attribute__((address_space(1))) void*)g,
                                     (__attribute__((address_space(3))) void*)l, 16, 0, 0);
}

// ---------- prep: combined, transposed f16 weights ----------
__global__ void prep_w(const float* __restrict__ wz1, const float* __restrict__ wh1,
                       const float* __restrict__ wz2, const float* __restrict__ wh2,
                       f16* __restrict__ W1T, f16* __restrict__ W2T) {
    const int b = blockIdx.x;
    if (b < 256) {
        int idx = b * 256 + threadIdx.x;
        int k = idx >> 8, c = idx & 255;
        const float* w = (c < 128) ? wz1 : wh1;
        int cc = c & 127;
        W1T[c * 256 + k] = (f16)(w[k * 128 + cc] + w[384 * 128 + k * 128 + cc]);
    } else {
        int idx = (b - 256) * 256 + threadIdx.x;
        int k = idx >> 7, c = idx & 127;
        const float* w = (c < 64) ? wz2 : wh2;
        int cc = c & 63;
        W2T[c * 128 + k] = (f16)(w[k * 64 + cc] + w[192 * 64 + k * 64 + cc]);
    }
}

// ---------- fused: 64 rows/block; X tile via one glds burst; barrier-free K-rounds ----------
__global__ __launch_bounds__(256, 2) void fused(
    const float* __restrict__ x,
    const f16* __restrict__ W1T, const f16* __restrict__ W2T,
    const float* __restrict__ bz1, const float* __restrict__ bh1,
    const float* __restrict__ bz2, const float* __restrict__ bh2,
    const float* __restrict__ wl1, const float* __restrict__ bl1,
    const float* __restrict__ wl2, const float* __restrict__ bl2,
    float* __restrict__ out)
{
    __shared__ __align__(16) float Xs[64 * 256];       // 64 KB, XOR-chunk-swizzled
    f16* h1s = (f16*)Xs;                               // overlay after P1 (17408 B)
    f16* h2s = (f16*)((char*)Xs + 17408);              // overlay (9216 B)

    const int tid = threadIdx.x, lane = tid & 63, wave = tid >> 6;
    const int ln = lane & 15, quad = lane >> 4;
    const int r0 = blockIdx.x * 64;

    // ---- stage X tile: wave w stages rows 16w..16w+15; slot s of row r holds chunk s^r ----
#pragma unroll
    for (int t = 0; t < 16; ++t) {
        const int r = wave * 16 + t;
        int gr = r0 + r; if (gr >= N_ROWS) gr = N_ROWS - 1;
        glds16(x + (size_t)gr * 256 + (((lane ^ r) & 63) << 2), &Xs[r * 256]);
    }

    // ---- W1 kc=0 frags in flight during the X wait ----
    // wave w: z m-tiles {2w,2w+1} (cols 32w..+31), h m-tiles {8+2w,9+2w}
    const f16* wbase[4];
#pragma unroll
    for (int mi = 0; mi < 4; ++mi) {
        const int M = (mi < 2) ? (2 * wave + mi) : (8 + 2 * wave + mi - 2);
        wbase[mi] = W1T + (size_t)(M * 16 + ln) * 256 + quad * 8;
    }
    f16x8 wc[4], wn[4];
#pragma unroll
    for (int mi = 0; mi < 4; ++mi) wc[mi] = *(const f16x8*)(wbase[mi]);

    __syncthreads();                                   // ONE vmcnt(0) drain + barrier

    f32x4 acc[4][4];                                   // [mi][nt]
#pragma unroll
    for (int a = 0; a < 4; ++a)
#pragma unroll
        for (int b = 0; b < 4; ++b) acc[a][b] = (f32x4){0.f, 0.f, 0.f, 0.f};

#pragma unroll
    for (int kc = 0; kc < 8; ++kc) {
#pragma unroll
        for (int mi = 0; mi < 4; ++mi)                 // next-round W (in flight over MFMAs)
            wn[mi] = *(const f16x8*)(wbase[mi] + (kc + 1) * 32);
        f16x8 bf[4];
#pragma unroll
        for (int nt = 0; nt < 4; ++nt) {
            const int row = 16 * nt + ln;
            const int c0 = kc * 8 + 2 * quad;
            float4 a = *(const float4*)&Xs[row * 256 + ((c0 ^ row) << 2)];
            float4 b = *(const float4*)&Xs[row * 256 + (((c0 + 1) ^ row) << 2)];
            bf[nt] = (f16x8){(f16)a.x,(f16)a.y,(f16)a.z,(f16)a.w,
                             (f16)b.x,(f16)b.y,(f16)b.z,(f16)b.w};
        }
#pragma unroll
        for (int mi = 0; mi < 4; ++mi)
#pragma unroll
            for (int nt = 0; nt < 4; ++nt)
                acc[mi][nt] = __builtin_amdgcn_mfma_f32_16x16x32_f16(wc[mi], bf[nt], acc[mi][nt], 0, 0, 0);
#pragma unroll
        for (int mi = 0; mi < 4; ++mi) wc[mi] = wn[mi];
    }
    __syncthreads();                                   // Xs reads done before h1s overlay

    // prefetch W2 frags (fly during epilogue): wave w -> z col-tile w, h col-tile w+4
    f16x8 w2f[2][4];
#pragma unroll
    for (int kc = 0; kc < 4; ++kc) {
        w2f[0][kc] = *(const f16x8*)(W2T + (size_t)(16 * wave + ln) * 128 + kc * 32 + quad * 8);
        w2f[1][kc] = *(const f16x8*)(W2T + (size_t)(64 + 16 * wave + ln) * 128 + kc * 32 + quad * 8);
    }

    // P1 epilogue: gates -> h1s. D: col(ln)=X row, row(4quad+i)=W col.
#pragma unroll
    for (int mi = 0; mi < 2; ++mi) {
        const int jg0 = 32 * wave + 16 * mi + (quad << 2);
        const float4 zb = *(const float4*)(bz1 + jg0);
        const float4 hb = *(const float4*)(bh1 + jg0);
#pragma unroll
        for (int nt = 0; nt < 4; ++nt) {
            const int row = 16 * nt + ln;
            f16x4 pk;
#pragma unroll
            for (int i = 0; i < 4; ++i) {
                float zp = acc[mi][nt][i]     + (&zb.x)[i];
                float hp = acc[mi + 2][nt][i] + (&hb.x)[i];
                float ex = __expf(2.0f * hp);
                float th = 1.0f - 2.0f / (ex + 1.0f);      // tanh
                float sg = 1.0f / (1.0f + __expf(zp));     // 1 - sigmoid
                pk[i] = (f16)fmaxf(th * sg, 0.0f);
            }
            *(f16x4*)&h1s[row * LSH1 + jg0] = pk;
        }
    }
    __syncthreads();

    // ---- P2: h2 = gates(h1 @ W2) ----
    f32x4 acc2[2][4];
#pragma unroll
    for (int a = 0; a < 2; ++a)
#pragma unroll
        for (int b = 0; b < 4; ++b) acc2[a][b] = (f32x4){0.f, 0.f, 0.f, 0.f};
#pragma unroll
    for (int kc = 0; kc < 4; ++kc) {
        f16x8 bf[4];
#pragma unroll
        for (int nt = 0; nt < 4; ++nt)
            bf[nt] = *(const f16x8*)&h1s[(16 * nt + ln) * LSH1 + kc * 32 + quad * 8];
#pragma unroll
        for (int m = 0; m < 2; ++m)
#pragma unroll
            for (int nt = 0; nt < 4; ++nt)
                acc2[m][nt] = __builtin_amdgcn_mfma_f32_16x16x32_f16(w2f[m][kc], bf[nt], acc2[m][nt], 0, 0, 0);
    }
    __syncthreads();                                   // h1s reads done (h2s region disjoint anyway)

    {
        const int jg0 = 16 * wave + (quad << 2);
        const float4 zb = *(const float4*)(bz2 + jg0);
        const float4 hb = *(const float4*)(bh2 + jg0);
#pragma unroll
        for (int nt = 0; nt < 4; ++nt) {
            const int row = 16 * nt + ln;
            f16x4 pk;
#pragma unroll
            for (int i = 0; i < 4; ++i) {
                float zp = acc2[0][nt][i] + (&zb.x)[i];
                float hp = acc2[1][nt][i] + (&hb.x)[i];
                float ex = __expf(2.0f * hp);
                float th = 1.0f - 2.0f / (ex + 1.0f);
                float sg = 1.0f / (1.0f + __expf(zp));
                pk[i] = (f16)fmaxf(th * sg, 0.0f);
            }
            *(f16x4*)&h2s[row * LSH2 + jg0] = pk;
        }
    }
    __syncthreads();

    // ---- P3: out = relu(h2 @ wl1 + bl1) @ wl2 + bl2 ----
    const float blv = bl1[ln], wlv = wl2[ln], bl2v = bl2[0];
    f16x8 bfr[2];
#pragma unroll
    for (int kc = 0; kc < 2; ++kc)
#pragma unroll
        for (int j = 0; j < 8; ++j)
            bfr[kc][j] = (f16)wl1[(32 * kc + 8 * quad + j) * 16 + ln];

    f32x4 acc3 = (f32x4){0.f, 0.f, 0.f, 0.f};
#pragma unroll
    for (int kc = 0; kc < 2; ++kc) {
        f16x8 af = *(const f16x8*)&h2s[(16 * wave + ln) * LSH2 + kc * 32 + quad * 8];
        acc3 = __builtin_amdgcn_mfma_f32_16x16x32_f16(af, bfr[kc], acc3, 0, 0, 0);
    }
#pragma unroll
    for (int i = 0; i < 4; ++i) {
        float v = fmaxf(acc3[i] + blv, 0.0f) * wlv;
        v += __shfl_xor(v, 1);
        v += __shfl_xor(v, 2);
        v += __shfl_xor(v, 4);
        v += __shfl_xor(v, 8);
        if (ln == 0) {
            const int row = r0 + 16 * wave + (quad << 2) + i;
            if (row < N_ROWS) out[row] = v + bl2v;
        }
    }
}

// ---------- launch ----------
extern "C" void kernel_launch(void* const* d_in, const int* in_sizes, int n_in,
                              void* d_out, int out_size, void* d_ws, size_t ws_size,
                              hipStream_t stream) {
    const float* x   = (const float*)d_in[0];
    const float* wz1 = (const float*)d_in[3];
    const float* bz1 = (const float*)d_in[4];
    const float* wh1 = (const float*)d_in[7];
    const float* bh1 = (const float*)d_in[8];
    const float* wz2 = (const float*)d_in[9];
    const float* bz2 = (const float*)d_in[10];
    const float* wh2 = (const float*)d_in[13];
    const float* bh2 = (const float*)d_in[14];
    const float* wl1 = (const float*)d_in[15];
    const float* bl1 = (const float*)d_in[16];
    const float* wl2 = (const float*)d_in[17];
    const float* bl2 = (const float*)d_in[18];

    char* ws = (char*)d_ws;
    f16* W1T = (f16*)(ws + W1T_OFF);
    f16* W2T = (f16*)(ws + W2T_OFF);
    float* out = (float*)d_out;

    prep_w<<<320, 256, 0, stream>>>(wz1, wh1, wz2, wh2, W1T, W2T);
    fused<<<RT, 256, 0, stream>>>(x, W1T, W2T, bz1, bh1, bz2, bh2,
                                  wl1, bl1, wl2, bl2, out);
}

// Round 8
// 242.091 us; speedup vs baseline: 1.0094x; 1.0094x over previous
//
#include <hip/hip_runtime.h>

// ---------- types ----------
typedef _Float16 f16;
typedef _Float16 f16x4 __attribute__((ext_vector_type(4)));
typedef _Float16 f16x8 __attribute__((ext_vector_type(8)));
typedef float    f32x4 __attribute__((ext_vector_type(4)));

#define N_ROWS 100000
#define RT 1563           // 1563 * 64 = 100032 padded rows
#define LSX 264           // X tile stride (f16): 132 dw = 4 mod 32 -> uniform banks
#define LSH1 136
#define LSH2 72

// ws: weights only
#define W1T_OFF 0
#define W1T_BYTES (256 * 256 * 2)
#define W2T_OFF W1T_BYTES

// ---------- prep: combined, transposed f16 weights ----------
__global__ void prep_w(const float* __restrict__ wz1, const float* __restrict__ wh1,
                       const float* __restrict__ wz2, const float* __restrict__ wh2,
                       f16* __restrict__ W1T, f16* __restrict__ W2T) {
    const int b = blockIdx.x;
    if (b < 256) {
        int idx = b * 256 + threadIdx.x;
        int k = idx >> 8, c = idx & 255;
        const float* w = (c < 128) ? wz1 : wh1;
        int cc = c & 127;
        W1T[c * 256 + k] = (f16)(w[k * 128 + cc] + w[384 * 128 + k * 128 + cc]);
    } else {
        int idx = (b - 256) * 256 + threadIdx.x;
        int k = idx >> 7, c = idx & 127;
        const float* w = (c < 64) ? wz2 : wh2;
        int cc = c & 63;
        W2T[c * 128 + k] = (f16)(w[k * 64 + cc] + w[192 * 64 + k * 64 + cc]);
    }
}

// ---------- fused: 64 rows/block; f16 X tile; immediate-offset K-loop; 4 blocks/CU ----------
__global__ __launch_bounds__(256, 4) void fused(
    const float* __restrict__ x,
    const f16* __restrict__ W1T, const f16* __restrict__ W2T,
    const float* __restrict__ bz1, const float* __restrict__ bh1,
    const float* __restrict__ bz2, const float* __restrict__ bh2,
    const float* __restrict__ wl1, const float* __restrict__ bl1,
    const float* __restrict__ wl2, const float* __restrict__ bl2,
    float* __restrict__ out)
{
    __shared__ __align__(16) f16 Xs[64 * LSX];         // 33792 B
    f16* h1s = Xs;                                     // overlay after K-loop (17408 B)
    f16* h2s = Xs + 8704;                              // byte 17408, 9216 B (disjoint)

    const int tid = threadIdx.x, lane = tid & 63, wave = tid >> 6;
    const int ln = lane & 15, quad = lane >> 4;
    const int r0 = blockIdx.x * 64;

    // ---- staging: batched f32 loads -> f16 cvt -> LDS (one barrier total) ----
    const int sr = tid >> 2;                           // row 0..63
    const int sc = (tid & 3) << 3;                     // col base {0,8,16,24}
    int gsr = r0 + sr; if (gsr >= N_ROWS) gsr = N_ROWS - 1;
    const float* xp = x + (size_t)gsr * 256 + sc;

    float4 va[8], vb[8];
#pragma unroll
    for (int g = 0; g < 8; ++g) {
        va[g] = *(const float4*)(xp + g * 32);
        vb[g] = *(const float4*)(xp + g * 32 + 4);
    }
    __builtin_amdgcn_sched_barrier(0);                 // keep all 16 loads batched

    // W1 kc=0 frags issued pre-barrier (overlap X drain).
    // wave w: z m-tiles {2w,2w+1} (cols 32w..+31), h m-tiles {8+2w,9+2w}
    const f16* wbase[4];
#pragma unroll
    for (int mi = 0; mi < 4; ++mi) {
        const int M = (mi < 2) ? (2 * wave + mi) : (8 + 2 * wave + mi - 2);
        wbase[mi] = W1T + (size_t)(M * 16 + ln) * 256 + quad * 8;
    }
    f16x8 wc[4];
#pragma unroll
    for (int mi = 0; mi < 4; ++mi) wc[mi] = *(const f16x8*)(wbase[mi]);

#pragma unroll
    for (int g = 0; g < 8; ++g)
        *(f16x8*)&Xs[sr * LSX + sc + g * 32] =
            (f16x8){(f16)va[g].x,(f16)va[g].y,(f16)va[g].z,(f16)va[g].w,
                    (f16)vb[g].x,(f16)vb[g].y,(f16)vb[g].z,(f16)vb[g].w};
    __syncthreads();

    // ---- P1 K-loop: 8 rounds, zero VALU (immediate offsets), W prefetch 1 ahead ----
    f32x4 acc[4][4];                                   // [mi][nt]
#pragma unroll
    for (int a = 0; a < 4; ++a)
#pragma unroll
        for (int b = 0; b < 4; ++b) acc[a][b] = (f32x4){0.f, 0.f, 0.f, 0.f};

    const f16* xrd = &Xs[ln * LSX + quad * 8];         // + nt*16*LSX + kc*32 (immediates)

#pragma unroll
    for (int kc = 0; kc < 8; ++kc) {
        f16x8 wn[4];
        if (kc < 7) {
#pragma unroll
            for (int mi = 0; mi < 4; ++mi)
                wn[mi] = *(const f16x8*)(wbase[mi] + (kc + 1) * 32);
        }
        f16x8 bf[4];
#pragma unroll
        for (int nt = 0; nt < 4; ++nt)
            bf[nt] = *(const f16x8*)(xrd + nt * 16 * LSX + kc * 32);
#pragma unroll
        for (int mi = 0; mi < 4; ++mi)
#pragma unroll
            for (int nt = 0; nt < 4; ++nt)
                acc[mi][nt] = __builtin_amdgcn_mfma_f32_16x16x32_f16(wc[mi], bf[nt], acc[mi][nt], 0, 0, 0);
        if (kc < 7) {
#pragma unroll
            for (int mi = 0; mi < 4; ++mi) wc[mi] = wn[mi];
        }
    }
    __syncthreads();                                   // Xs reads done before h1s overlay

    // W2 frags prefetch (fly during epilogue): wave w -> z col-tile w, h col-tile w+4
    f16x8 w2f[2][4];
#pragma unroll
    for (int kc = 0; kc < 4; ++kc) {
        w2f[0][kc] = *(const f16x8*)(W2T + (size_t)(16 * wave + ln) * 128 + kc * 32 + quad * 8);
        w2f[1][kc] = *(const f16x8*)(W2T + (size_t)(64 + 16 * wave + ln) * 128 + kc * 32 + quad * 8);
    }

    // P1 epilogue: gates -> h1s. D: col(ln)=X row, row(4quad+i)=W col.
#pragma unroll
    for (int mi = 0; mi < 2; ++mi) {
        const int jg0 = 32 * wave + 16 * mi + (quad << 2);
        const float4 zb = *(const float4*)(bz1 + jg0);
        const float4 hb = *(const float4*)(bh1 + jg0);
#pragma unroll
        for (int nt = 0; nt < 4; ++nt) {
            const int row = 16 * nt + ln;
            f16x4 pk;
#pragma unroll
            for (int i = 0; i < 4; ++i) {
                float zp = acc[mi][nt][i]     + (&zb.x)[i];
                float hp = acc[mi + 2][nt][i] + (&hb.x)[i];
                float ex = __expf(2.0f * hp);
                float th = 1.0f - 2.0f / (ex + 1.0f);      // tanh
                float sg = 1.0f / (1.0f + __expf(zp));     // 1 - sigmoid
                pk[i] = (f16)fmaxf(th * sg, 0.0f);
            }
            *(f16x4*)&h1s[row * LSH1 + jg0] = pk;
        }
    }
    __syncthreads();

    // ---- P2: h2 = gates(h1 @ W2) ----
    f32x4 acc2[2][4];
#pragma unroll
    for (int a = 0; a < 2; ++a)
#pragma unroll
        for (int b = 0; b < 4; ++b) acc2[a][b] = (f32x4){0.f, 0.f, 0.f, 0.f};
#pragma unroll
    for (int kc = 0; kc < 4; ++kc) {
        f16x8 bf[4];
#pragma unroll
        for (int nt = 0; nt < 4; ++nt)
            bf[nt] = *(const f16x8*)&h1s[(16 * nt + ln) * LSH1 + kc * 32 + quad * 8];
#pragma unroll
        for (int m = 0; m < 2; ++m)
#pragma unroll
            for (int nt = 0; nt < 4; ++nt)
                acc2[m][nt] = __builtin_amdgcn_mfma_f32_16x16x32_f16(w2f[m][kc], bf[nt], acc2[m][nt], 0, 0, 0);
    }

    {   // h2s is disjoint from h1s -> no barrier needed before writes
        const int jg0 = 16 * wave + (quad << 2);
        const float4 zb = *(const float4*)(bz2 + jg0);
        const float4 hb = *(const float4*)(bh2 + jg0);
#pragma unroll
        for (int nt = 0; nt < 4; ++nt) {
            const int row = 16 * nt + ln;
            f16x4 pk;
#pragma unroll
            for (int i = 0; i < 4; ++i) {
                float zp = acc2[0][nt][i] + (&zb.x)[i];
                float hp = acc2[1][nt][i] + (&hb.x)[i];
                float ex = __expf(2.0f * hp);
                float th = 1.0f - 2.0f / (ex + 1.0f);
                float sg = 1.0f / (1.0f + __expf(zp));
                pk[i] = (f16)fmaxf(th * sg, 0.0f);
            }
            *(f16x4*)&h2s[row * LSH2 + jg0] = pk;
        }
    }
    __syncthreads();

    // ---- P3: out = relu(h2 @ wl1 + bl1) @ wl2 + bl2 ----
    const float blv = bl1[ln], wlv = wl2[ln], bl2v = bl2[0];
    f16x8 bfr[2];
#pragma unroll
    for (int kc = 0; kc < 2; ++kc)
#pragma unroll
        for (int j = 0; j < 8; ++j)
            bfr[kc][j] = (f16)wl1[(32 * kc + 8 * quad + j) * 16 + ln];

    f32x4 acc3 = (f32x4){0.f, 0.f, 0.f, 0.f};
#pragma unroll
    for (int kc = 0; kc < 2; ++kc) {
        f16x8 af = *(const f16x8*)&h2s[(16 * wave + ln) * LSH2 + kc * 32 + quad * 8];
        acc3 = __builtin_amdgcn_mfma_f32_16x16x32_f16(af, bfr[kc], acc3, 0, 0, 0);
    }
#pragma unroll
    for (int i = 0; i < 4; ++i) {
        float v = fmaxf(acc3[i] + blv, 0.0f) * wlv;
        v += __shfl_xor(v, 1);
        v += __shfl_xor(v, 2);
        v += __shfl_xor(v, 4);
        v += __shfl_xor(v, 8);
        if (ln == 0) {
            const int row = r0 + 16 * wave + (quad << 2) + i;
            if (row < N_ROWS) out[row] = v + bl2v;
        }
    }
}

// ---------- launch ----------
extern "C" void kernel_launch(void* const* d_in, const int* in_sizes, int n_in,
                              void* d_out, int out_size, void* d_ws, size_t ws_size,
                              hipStream_t stream) {
    const float* x   = (const float*)d_in[0];
    const float* wz1 = (const float*)d_in[3];
    const float* bz1 = (const float*)d_in[4];
    const float* wh1 = (const float*)d_in[7];
    const float* bh1 = (const float*)d_in[8];
    const float* wz2 = (const float*)d_in[9];
    const float* bz2 = (const float*)d_in[10];
    const float* wh2 = (const float*)d_in[13];
    const float* bh2 = (const float*)d_in[14];
    const float* wl1 = (const float*)d_in[15];
    const float* bl1 = (const float*)d_in[16];
    const float* wl2 = (const float*)d_in[17];
    const float* bl2 = (const float*)d_in[18];

    char* ws = (char*)d_ws;
    f16* W1T = (f16*)(ws + W1T_OFF);
    f16* W2T = (f16*)(ws + W2T_OFF);
    float* out = (float*)d_out;

    prep_w<<<320, 256, 0, stream>>>(wz1, wh1, wz2, wh2, W1T, W2T);
    fused<<<RT, 256, 0, stream>>>(x, W1T, W2T, bz1, bh1, bz2, bh2,
                                  wl1, bl1, wl2, bl2, out);
}